// Round 16
// baseline (282.390 us; speedup 1.0000x reference)
//
#include <hip/hip_runtime.h>
#include <hip/hip_bf16.h>
#include <hip/hip_fp16.h>
#include <math.h>

#define ND 128      // feature dim D
#define NH 4        // heads
#define HD 512      // H*D

typedef __attribute__((ext_vector_type(8))) short bf16x8;
typedef __attribute__((ext_vector_type(4))) float f32x4;

__device__ __forceinline__ unsigned pack_bf16(float a, float b) {
    unsigned ua = __float_as_uint(a), ub = __float_as_uint(b);
    ua = (ua + 0x7fffu + ((ua >> 16) & 1u)) >> 16;
    ub = (ub + 0x7fffu + ((ub >> 16) & 1u)) >> 16;
    return ua | (ub << 16);
}
__device__ __forceinline__ unsigned short bf16r(float a) {
    unsigned ua = __float_as_uint(a);
    return (unsigned short)((ua + 0x7fffu + ((ua >> 16) & 1u)) >> 16);
}
__device__ __forceinline__ float bflo(unsigned u) { return __uint_as_float(u << 16); }
__device__ __forceinline__ float bfhi(unsigned u) { return __uint_as_float(u & 0xffff0000u); }

// ---------------------------------------------------------------------------
// K0 v2: blocks [0,16): W 64x64 LDS-tile transposes -> Ws[j][h*128+k] bf16.
//        blocks [16,48): pt — wave per k (coalesced W row reads + shfl).
//        blocks [48, ...): dst histogram.
// ---------------------------------------------------------------------------
__global__ __launch_bounds__(256) void prep_misc(const float* __restrict__ W,
                                                 const float* __restrict__ att_src,
                                                 const float* __restrict__ att_dst,
                                                 unsigned short* __restrict__ Ws,
                                                 float* __restrict__ pt,
                                                 const int* __restrict__ dst,
                                                 int* __restrict__ cnt, int ne) {
    int b = blockIdx.x;
    if (b < 16) {
        __shared__ float tile[64][65];
        int h = b >> 2, rt = (b >> 1) & 1, ct = b & 1;
        int tx = threadIdx.x;
        int rr = tx >> 6, c = tx & 63;
#pragma unroll
        for (int i = 0; i < 16; ++i) {
            int r = i * 4 + rr;
            tile[r][c] = W[(size_t)(rt * 64 + r) * HD + h * ND + ct * 64 + c];
        }
        __syncthreads();
#pragma unroll
        for (int i = 0; i < 16; ++i) {
            int r = i * 4 + rr;   // j-local
            Ws[(size_t)(ct * 64 + r) * HD + h * ND + rt * 64 + c] = bf16r(tile[c][r]);
        }
    } else if (b < 48) {
        int w = threadIdx.x >> 6, lane = threadIdx.x & 63;
        int k = (b - 16) * 4 + w;   // 0..127
#pragma unroll
        for (int h = 0; h < NH; ++h) {
            float2 wv = ((const float2*)(W + (size_t)k * HD + h * ND))[lane];
            float2 as = ((const float2*)(att_src + h * ND))[lane];
            float2 ad = ((const float2*)(att_dst + h * ND))[lane];
            float ps = wv.x * as.x + wv.y * as.y;
            float pd = wv.x * ad.x + wv.y * ad.y;
#pragma unroll
            for (int off = 1; off < 64; off <<= 1) {
                ps += __shfl_xor(ps, off);
                pd += __shfl_xor(pd, off);
            }
            if (lane == 0) {
                pt[h * ND + k] = ps;
                pt[(4 + h) * ND + k] = pd;
            }
        }
    } else {
        int e = (b - 48) * 256 + threadIdx.x;
        if (e < ne) atomicAdd(&cnt[dst[e]], 1);
    }
}

// ---------------------------------------------------------------------------
// K1 fused: blocks [0, nbA): k_a_xb; blocks [nbA, nbA+nbS): scanA over cnt.
// ---------------------------------------------------------------------------
__global__ __launch_bounds__(256) void ka_scanA(const float* __restrict__ x,
                                                const float* __restrict__ pt,
                                                unsigned* __restrict__ xb,
                                                float* __restrict__ a_src,
                                                float* __restrict__ a_dst,
                                                const int* __restrict__ cnt,
                                                int* __restrict__ partial,
                                                int* __restrict__ bsum,
                                                int n, int nbA) {
    __shared__ float pl[8 * ND];
    __shared__ int sh[256];
    if ((int)blockIdx.x < nbA) {
        { int t = threadIdx.x; ((float4*)pl)[t] = ((const float4*)pt)[t]; }
        __syncthreads();
        int wave = (blockIdx.x * 256 + threadIdx.x) >> 6;
        int lane = threadIdx.x & 63;
        if (wave >= n) return;
        float2 xv = ((const float2*)(x + (size_t)wave * ND))[lane];
        xb[(size_t)wave * 64 + lane] = pack_bf16(xv.x, xv.y);
#pragma unroll
        for (int o = 0; o < 8; ++o) {
            float2 pv = ((const float2*)(pl + o * ND))[lane];
            float v = xv.x * pv.x + xv.y * pv.y;
#pragma unroll
            for (int off = 1; off < 64; off <<= 1) v += __shfl_xor(v, off);
            if (lane == 0) {
                if (o < 4) a_src[(size_t)wave * NH + o] = v;
                else       a_dst[(size_t)wave * NH + (o - 4)] = v;
            }
        }
    } else {
        int bid = blockIdx.x - nbA;
        int gid = bid * 256 + threadIdx.x;
        int v = (gid < n) ? cnt[gid] : 0;
        int val = v;
        sh[threadIdx.x] = val;
        __syncthreads();
#pragma unroll
        for (int off = 1; off < 256; off <<= 1) {
            int add = (threadIdx.x >= off) ? sh[threadIdx.x - off] : 0;
            __syncthreads();
            val += add;
            sh[threadIdx.x] = val;
            __syncthreads();
        }
        if (gid < n) partial[gid] = val - v;
        if (threadIdx.x == 255) bsum[bid] = val;
    }
}

// ---------------------------------------------------------------------------
// scanBC: redundant block-sum scan + apply offset.
// ---------------------------------------------------------------------------
__global__ __launch_bounds__(256) void scanBC(const int* __restrict__ partial,
                                              const int* __restrict__ bsum,
                                              int* __restrict__ starts,
                                              int* __restrict__ cursor,
                                              int n, int ne, int nb) {
    __shared__ int sh[256];
    int t = threadIdx.x;
    int v = (t < nb) ? bsum[t] : 0;
    int val = v;
    sh[t] = val;
    __syncthreads();
#pragma unroll
    for (int off = 1; off < 256; off <<= 1) {
        int add = (t >= off) ? sh[t - off] : 0;
        __syncthreads();
        val += add;
        sh[t] = val;
        __syncthreads();
    }
    int myoff = (blockIdx.x == 0) ? 0 : sh[blockIdx.x - 1];
    int gid = blockIdx.x * 256 + t;
    if (gid < n) {
        int s = partial[gid] + myoff;
        starts[gid] = s;
        cursor[gid] = s;
    }
    if (gid == 0) starts[n] = ne;
}

// ---------------------------------------------------------------------------
// K_scatter: dst-segment permute + BF16 head weights: {src, w01, w23, pad}.
// (bf16 so node_agg can feed them straight into the MFMA A operand.)
// ---------------------------------------------------------------------------
__global__ __launch_bounds__(256) void scatter_edges_w(const int* __restrict__ src,
                                                       const int* __restrict__ dst,
                                                       const float* __restrict__ a_src,
                                                       const float* __restrict__ a_dst,
                                                       int* __restrict__ cursor,
                                                       uint4* __restrict__ eperm, int ne) {
    int e = blockIdx.x * 256 + threadIdx.x;
    if (e < ne) {
        int s = src[e], t = dst[e];
        float4 as = *(const float4*)(a_src + (size_t)s * NH);
        float4 ad = *(const float4*)(a_dst + (size_t)t * NH);
        float A0 = as.x + ad.x, A1 = as.y + ad.y, A2 = as.z + ad.z, A3 = as.w + ad.w;
        A0 = (A0 > 0.f) ? A0 : 0.2f * A0;
        A1 = (A1 > 0.f) ? A1 : 0.2f * A1;
        A2 = (A2 > 0.f) ? A2 : 0.2f * A2;
        A3 = (A3 > 0.f) ? A3 : 0.2f * A3;
        float e0 = __expf(A0), e1 = __expf(A1), e2 = __expf(A2), e3 = __expf(A3);
        int pos = atomicAdd(&cursor[t], 1);
        uint4 ev;
        ev.x = (unsigned)s;
        ev.y = pack_bf16(e0, e1);
        ev.z = pack_bf16(e2, e3);
        ev.w = 0u;
        eperm[pos] = ev;
    }
}

// ---------------------------------------------------------------------------
// K_agg v6 (MFMA): 2 waves per node, each owns a 64-dim half. Per 32-edge
// chunk: gather bf16 x half-rows (4 uint4 loads), write TRANSPOSED into
// per-wave LDS [4 blk][16 dims][80B-stride rows of 32 edges]; weights
// [16][80B] (rows 0-3 = heads). Then A = ds_read_b128 (w[head][8g..8g+7]),
// B = ds_read_b128 per dim-block, 4x mfma_f32_16x16x32_bf16:
//   C[head][dim] += sum_e w[head][e] * x[e][dim]
// C layout: col=lane&15 (dim), row=(lane>>4)*4+ri (head; lanes 0-15 hold all
// heads). Epilogue: per-head normalize, 16 bf16 stores to u.
// No barriers (per-wave LDS regions); heads complete within each wave.
// ---------------------------------------------------------------------------
__global__ __launch_bounds__(256) void node_agg(const uint4* __restrict__ eperm,
                                                const int* __restrict__ starts,
                                                const unsigned* __restrict__ xb,
                                                unsigned* __restrict__ u, int n) {
    __shared__ char ldsb[4 * 6400];
    const int w = threadIdx.x >> 6;
    const int lane = threadIdx.x & 63;
    const int node = blockIdx.x * 2 + (w >> 1);
    const int wh = w & 1;               // dim half: dims wh*64 .. +63
    char* xT = ldsb + w * 6400;         // 4 blocks x [16 dims][80B]
    char* wT = xT + 5120;               // [16 heads][80B]
    if (node >= n) return;

    const int e16 = lane & 15, g = lane >> 4;
    const char* xbb = (const char*)xb;

    int s0 = starts[node], s1 = starts[node + 1];

    float den0 = 0.f, den1 = 0.f, den2 = 0.f, den3 = 0.f;
    f32x4 acc[4];
#pragma unroll
    for (int b = 0; b < 4; ++b) acc[b] = (f32x4){0.f, 0.f, 0.f, 0.f};

    for (int base = s0; base < s1; base += 32) {
        int rem = s1 - base; if (rem > 32) rem = 32;
        uint4 ev = {0u, 0u, 0u, 0u};
        if (lane < rem) ev = eperm[base + lane];
        // denominators (bf16 weights; zero on pad lanes)
        den0 += bflo(ev.y); den1 += bfhi(ev.y);
        den2 += bflo(ev.z); den3 += bfhi(ev.z);
        // stage weights: lane e (0..31) writes w[h][e] for h=0..3
        if (lane < 32) {
            *(unsigned short*)(wT + 0 * 80 + lane * 2) = (unsigned short)(ev.y & 0xffffu);
            *(unsigned short*)(wT + 1 * 80 + lane * 2) = (unsigned short)(ev.y >> 16);
            *(unsigned short*)(wT + 2 * 80 + lane * 2) = (unsigned short)(ev.z & 0xffffu);
            *(unsigned short*)(wT + 3 * 80 + lane * 2) = (unsigned short)(ev.z >> 16);
        }
        // gather + transpose-stage: 4 instrs, 8 edges each; lane covers 8 dims
#pragma unroll
        for (int i = 0; i < 4; ++i) {
            int r = i * 8 + (lane >> 3);          // edge slot 0..31
            int srcn = __shfl((int)ev.x, r);
            uint4 pv = {0u, 0u, 0u, 0u};
            if (r < rem)
                pv = *(const uint4*)(xbb + (size_t)srcn * 256 + wh * 128 + (lane & 7) * 16);
            char* bb = xT + ((lane & 7) >> 1) * 1280 + (((lane & 7) & 1) * 8) * 80 + r * 2;
            *(unsigned short*)(bb + 0 * 80) = (unsigned short)(pv.x & 0xffffu);
            *(unsigned short*)(bb + 1 * 80) = (unsigned short)(pv.x >> 16);
            *(unsigned short*)(bb + 2 * 80) = (unsigned short)(pv.y & 0xffffu);
            *(unsigned short*)(bb + 3 * 80) = (unsigned short)(pv.y >> 16);
            *(unsigned short*)(bb + 4 * 80) = (unsigned short)(pv.z & 0xffffu);
            *(unsigned short*)(bb + 5 * 80) = (unsigned short)(pv.z >> 16);
            *(unsigned short*)(bb + 6 * 80) = (unsigned short)(pv.w & 0xffffu);
            *(unsigned short*)(bb + 7 * 80) = (unsigned short)(pv.w >> 16);
        }
        // MFMA: A = weights (row=head, k=edge 8g..8g+7), B = x (col=dim, same k)
        bf16x8 Af = *(const bf16x8*)(wT + e16 * 80 + g * 16);
#pragma unroll
        for (int b = 0; b < 4; ++b) {
            bf16x8 Bf = *(const bf16x8*)(xT + b * 1280 + e16 * 80 + g * 16);
            acc[b] = __builtin_amdgcn_mfma_f32_16x16x32_bf16(Af, Bf, acc[b], 0, 0, 0);
        }
    }

    // reduce denominators over all 64 lanes
#pragma unroll
    for (int off = 1; off < 64; off <<= 1) {
        den0 += __shfl_xor(den0, off);
        den1 += __shfl_xor(den1, off);
        den2 += __shfl_xor(den2, off);
        den3 += __shfl_xor(den3, off);
    }
    float ih0 = (den0 > 0.f) ? 0.25f / den0 : 0.f;
    float ih1 = (den1 > 0.f) ? 0.25f / den1 : 0.f;
    float ih2 = (den2 > 0.f) ? 0.25f / den2 : 0.f;
    float ih3 = (den3 > 0.f) ? 0.25f / den3 : 0.f;

    if (g == 0) {   // lanes 0-15 hold head rows 0-3 (ri = head)
        unsigned short* uu = (unsigned short*)u + (size_t)node * HD;
#pragma unroll
        for (int b = 0; b < 4; ++b) {
            int dcol = wh * 64 + b * 16 + e16;
            uu[0 * ND + dcol] = bf16r(acc[b][0] * ih0);
            uu[1 * ND + dcol] = bf16r(acc[b][1] * ih1);
            uu[2 * ND + dcol] = bf16r(acc[b][2] * ih2);
            uu[3 * ND + dcol] = bf16r(acc[b][3] * ih3);
        }
    }
}

// ---------------------------------------------------------------------------
// K_out v4 (R14-proven): agg = u [N,512] @ Ws^T via MFMA. 128 rows/block,
// B chunk (32KB) staged in LDS per kc; A streams direct from global.
// Register epilogue: bias + LN (shfl over 16-lane col group) + GELU + res.
// ---------------------------------------------------------------------------
__global__ __launch_bounds__(256) void gemm_out(
        const unsigned short* __restrict__ u, const unsigned short* __restrict__ Ws,
        const float* __restrict__ x, const float* __restrict__ bias,
        const float* __restrict__ gamma, const float* __restrict__ beta,
        float* __restrict__ out, int n) {
    __shared__ char Bs[32768];
    const int t = threadIdx.x;
    const int w = t >> 6, l = t & 63;
    const int e16 = l & 15, g16 = l >> 4;
    const int row0 = blockIdx.x * 128;

    int ar0 = row0 + w * 32 + e16;      if (ar0 >= n) ar0 = n - 1;
    int ar1 = row0 + w * 32 + 16 + e16; if (ar1 >= n) ar1 = n - 1;
    const unsigned short* ap0 = u + (size_t)ar0 * HD + g16 * 8;
    const unsigned short* ap1 = u + (size_t)ar1 * HD + g16 * 8;

    f32x4 acc[2][8];
#pragma unroll
    for (int mt = 0; mt < 2; ++mt)
#pragma unroll
        for (int nr = 0; nr < 8; ++nr) acc[mt][nr] = (f32x4){0.f, 0.f, 0.f, 0.f};

    const int swz = (e16 & 7) << 4;
    for (int kc = 0; kc < 4; ++kc) {
        if (kc) __syncthreads();
#pragma unroll
        for (int i = 0; i < 8; ++i) {
            int c = t + i * 256;
            int nl = c >> 4, kb = c & 15;
            uint4 pv = *(const uint4*)(Ws + (size_t)nl * HD + kc * 128 + kb * 8);
            *(uint4*)(Bs + nl * 256 + ((kb * 16) ^ ((nl & 7) << 4))) = pv;
        }
        __syncthreads();

#pragma unroll
        for (int ks = 0; ks < 4; ++ks) {
            int koff = (ks * 64 + g16 * 16) ^ swz;
            bf16x8 a0 = *(const bf16x8*)(ap0 + kc * 128 + ks * 32);
            bf16x8 a1 = *(const bf16x8*)(ap1 + kc * 128 + ks * 32);
#pragma unroll
            for (int nr = 0; nr < 8; ++nr) {
                bf16x8 b = *(const bf16x8*)(Bs + (nr * 16 + e16) * 256 + koff);
                acc[0][nr] = __builtin_amdgcn_mfma_f32_16x16x32_bf16(a0, b, acc[0][nr], 0, 0, 0);
                acc[1][nr] = __builtin_amdgcn_mfma_f32_16x16x32_bf16(a1, b, acc[1][nr], 0, 0, 0);
            }
        }
    }

    float bias_l[8], gam_l[8], bet_l[8];
#pragma unroll
    for (int c = 0; c < 8; ++c) {
        bias_l[c] = bias[c * 16 + e16];
        gam_l[c]  = gamma[c * 16 + e16];
        bet_l[c]  = beta[c * 16 + e16];
    }
#pragma unroll
    for (int mt = 0; mt < 2; ++mt) {
#pragma unroll
        for (int ri = 0; ri < 4; ++ri) {
            int grow = row0 + w * 32 + mt * 16 + g16 * 4 + ri;
            float val[8];
            float s = 0.f, s2 = 0.f;
#pragma unroll
            for (int c = 0; c < 8; ++c) {
                val[c] = acc[mt][c][ri] + bias_l[c];
                s += val[c]; s2 += val[c] * val[c];
            }
#pragma unroll
            for (int off = 1; off < 16; off <<= 1) {
                s += __shfl_xor(s, off);
                s2 += __shfl_xor(s2, off);
            }
            float mu = s * (1.0f / ND);
            float var = fmaxf(s2 * (1.0f / ND) - mu * mu, 0.0f);
            float inv = rsqrtf(var + 1e-5f);
            if (grow < n) {
#pragma unroll
                for (int c = 0; c < 8; ++c) {
                    float y = (val[c] - mu) * inv * gam_l[c] + bet_l[c];
                    y = 0.5f * y * (1.0f + erff(y * 0.70710678118654752f));
                    out[(size_t)grow * ND + c * 16 + e16] =
                        y + x[(size_t)grow * ND + c * 16 + e16];
                }
            }
        }
    }
}

// ---------------------------------------------------------------------------
extern "C" void kernel_launch(void* const* d_in, const int* in_sizes, int n_in,
                              void* d_out, int out_size, void* d_ws, size_t ws_size,
                              hipStream_t stream) {
    const float* x       = (const float*)d_in[0];
    const int*   edge    = (const int*)d_in[1];   // [2, E]: src row then dst row
    const float* W       = (const float*)d_in[2];
    const float* att_src = (const float*)d_in[3];
    const float* att_dst = (const float*)d_in[4];
    const float* bias    = (const float*)d_in[5];
    const float* gamma   = (const float*)d_in[6];
    const float* beta    = (const float*)d_in[7];
    float* out = (float*)d_out;

    const int n  = in_sizes[0] / ND;   // 50000
    const int ne = in_sizes[1] / 2;    // 800000
    const int* src = edge;
    const int* dst = edge + ne;

    const int nb  = (n + 255) / 256;   // 196 (<256)
    const int nbA = (n + 3) / 4;       // k_a_xb blocks (12500)

    char* wsp = (char*)d_ws;
    unsigned* xb        = (unsigned*)wsp;        wsp += (size_t)n * 64 * sizeof(unsigned);   // bf16 x copy
    unsigned short* u   = (unsigned short*)wsp;  wsp += (size_t)n * HD * sizeof(short);      // weighted sums
    unsigned short* Ws  = (unsigned short*)wsp;  wsp += (size_t)ND * HD * sizeof(short);     // [j][K] bf16
    float* pt      = (float*)wsp;               wsp += (size_t)8 * ND * sizeof(float);
    float* a_src   = (float*)wsp;               wsp += (size_t)n * NH * sizeof(float);
    float* a_dst   = (float*)wsp;               wsp += (size_t)n * NH * sizeof(float);
    uint4* eperm   = (uint4*)wsp;               wsp += (size_t)ne * sizeof(uint4);
    int*   cnt     = (int*)wsp;                 wsp += (size_t)n * sizeof(int);
    int*   partial = (int*)wsp;                 wsp += (size_t)n * sizeof(int);
    int*   bsum    = (int*)wsp;                 wsp += 256 * sizeof(int);
    int*   starts  = (int*)wsp;                 wsp += (size_t)(n + 1) * sizeof(int);
    int*   cursor  = (int*)wsp;                 wsp += (size_t)n * sizeof(int);

    (void)hipMemsetAsync(cnt, 0, (size_t)n * sizeof(int), stream);

    prep_misc<<<48 + (ne + 255) / 256, 256, 0, stream>>>(W, att_src, att_dst,
                                                         Ws, pt, dst, cnt, ne);

    ka_scanA<<<nbA + nb, 256, 0, stream>>>(x, pt, xb, a_src, a_dst,
                                           cnt, partial, bsum, n, nbA);

    scanBC<<<nb, 256, 0, stream>>>(partial, bsum, starts, cursor, n, ne, nb);

    scatter_edges_w<<<(ne + 255) / 256, 256, 0, stream>>>(src, dst, a_src, a_dst,
                                                          cursor, eperm, ne);

    node_agg<<<(n + 1) / 2, 256, 0, stream>>>(eperm, starts, xb, (unsigned*)u, n);

    gemm_out<<<(n + 127) / 128, 256, 0, stream>>>(u, Ws, x, bias, gamma, beta, out, n);
}

// Round 17
// 210.571 us; speedup vs baseline: 1.3411x; 1.3411x over previous
//
#include <hip/hip_runtime.h>
#include <hip/hip_bf16.h>
#include <hip/hip_fp16.h>
#include <math.h>

#define ND 128      // feature dim D
#define NH 4        // heads
#define HD 512      // H*D

typedef __attribute__((ext_vector_type(8))) short bf16x8;
typedef __attribute__((ext_vector_type(4))) float f32x4;
typedef __attribute__((ext_vector_type(2))) float f32x2;

__device__ __forceinline__ unsigned pack_bf16(float a, float b) {
    unsigned ua = __float_as_uint(a), ub = __float_as_uint(b);
    ua = (ua + 0x7fffu + ((ua >> 16) & 1u)) >> 16;
    ub = (ub + 0x7fffu + ((ub >> 16) & 1u)) >> 16;
    return ua | (ub << 16);
}
__device__ __forceinline__ unsigned short bf16r(float a) {
    unsigned ua = __float_as_uint(a);
    return (unsigned short)((ua + 0x7fffu + ((ua >> 16) & 1u)) >> 16);
}
__device__ __forceinline__ float bflo(unsigned u) { return __uint_as_float(u << 16); }
__device__ __forceinline__ float bfhi(unsigned u) { return __uint_as_float(u & 0xffff0000u); }
__device__ __forceinline__ unsigned pack_half2(float a, float b) {
    __half ha = __float2half(a), hb = __float2half(b);
    return (unsigned)__half_as_ushort(ha) | ((unsigned)__half_as_ushort(hb) << 16);
}
__device__ __forceinline__ float2 h22f(unsigned u) {
    __half2 h = *(__half2*)&u;
    return __half22float2(h);
}

// ---------------------------------------------------------------------------
// K0 v2: blocks [0,16): W 64x64 LDS-tile transposes -> Ws[j][h*128+k] bf16.
//        blocks [16,48): pt — wave per k (coalesced W row reads + shfl).
//        blocks [48, ...): dst histogram.
// ---------------------------------------------------------------------------
__global__ __launch_bounds__(256) void prep_misc(const float* __restrict__ W,
                                                 const float* __restrict__ att_src,
                                                 const float* __restrict__ att_dst,
                                                 unsigned short* __restrict__ Ws,
                                                 float* __restrict__ pt,
                                                 const int* __restrict__ dst,
                                                 int* __restrict__ cnt, int ne) {
    int b = blockIdx.x;
    if (b < 16) {
        __shared__ float tile[64][65];
        int h = b >> 2, rt = (b >> 1) & 1, ct = b & 1;
        int tx = threadIdx.x;
        int rr = tx >> 6, c = tx & 63;
#pragma unroll
        for (int i = 0; i < 16; ++i) {
            int r = i * 4 + rr;
            tile[r][c] = W[(size_t)(rt * 64 + r) * HD + h * ND + ct * 64 + c];
        }
        __syncthreads();
#pragma unroll
        for (int i = 0; i < 16; ++i) {
            int r = i * 4 + rr;   // j-local
            Ws[(size_t)(ct * 64 + r) * HD + h * ND + rt * 64 + c] = bf16r(tile[c][r]);
        }
    } else if (b < 48) {
        int w = threadIdx.x >> 6, lane = threadIdx.x & 63;
        int k = (b - 16) * 4 + w;   // 0..127
#pragma unroll
        for (int h = 0; h < NH; ++h) {
            float2 wv = ((const float2*)(W + (size_t)k * HD + h * ND))[lane];
            float2 as = ((const float2*)(att_src + h * ND))[lane];
            float2 ad = ((const float2*)(att_dst + h * ND))[lane];
            float ps = wv.x * as.x + wv.y * as.y;
            float pd = wv.x * ad.x + wv.y * ad.y;
#pragma unroll
            for (int off = 1; off < 64; off <<= 1) {
                ps += __shfl_xor(ps, off);
                pd += __shfl_xor(pd, off);
            }
            if (lane == 0) {
                pt[h * ND + k] = ps;
                pt[(4 + h) * ND + k] = pd;
            }
        }
    } else {
        int e = (b - 48) * 256 + threadIdx.x;
        if (e < ne) atomicAdd(&cnt[dst[e]], 1);
    }
}

// ---------------------------------------------------------------------------
// K1 fused: blocks [0, nbA): k_a_xb; blocks [nbA, nbA+nbS): scanA over cnt.
// ---------------------------------------------------------------------------
__global__ __launch_bounds__(256) void ka_scanA(const float* __restrict__ x,
                                                const float* __restrict__ pt,
                                                unsigned* __restrict__ xb,
                                                float* __restrict__ a_src,
                                                float* __restrict__ a_dst,
                                                const int* __restrict__ cnt,
                                                int* __restrict__ partial,
                                                int* __restrict__ bsum,
                                                int n, int nbA) {
    __shared__ float pl[8 * ND];
    __shared__ int sh[256];
    if ((int)blockIdx.x < nbA) {
        { int t = threadIdx.x; ((float4*)pl)[t] = ((const float4*)pt)[t]; }
        __syncthreads();
        int wave = (blockIdx.x * 256 + threadIdx.x) >> 6;
        int lane = threadIdx.x & 63;
        if (wave >= n) return;
        float2 xv = ((const float2*)(x + (size_t)wave * ND))[lane];
        xb[(size_t)wave * 64 + lane] = pack_bf16(xv.x, xv.y);
#pragma unroll
        for (int o = 0; o < 8; ++o) {
            float2 pv = ((const float2*)(pl + o * ND))[lane];
            float v = xv.x * pv.x + xv.y * pv.y;
#pragma unroll
            for (int off = 1; off < 64; off <<= 1) v += __shfl_xor(v, off);
            if (lane == 0) {
                if (o < 4) a_src[(size_t)wave * NH + o] = v;
                else       a_dst[(size_t)wave * NH + (o - 4)] = v;
            }
        }
    } else {
        int bid = blockIdx.x - nbA;
        int gid = bid * 256 + threadIdx.x;
        int v = (gid < n) ? cnt[gid] : 0;
        int val = v;
        sh[threadIdx.x] = val;
        __syncthreads();
#pragma unroll
        for (int off = 1; off < 256; off <<= 1) {
            int add = (threadIdx.x >= off) ? sh[threadIdx.x - off] : 0;
            __syncthreads();
            val += add;
            sh[threadIdx.x] = val;
            __syncthreads();
        }
        if (gid < n) partial[gid] = val - v;
        if (threadIdx.x == 255) bsum[bid] = val;
    }
}

// ---------------------------------------------------------------------------
// scanBC: redundant block-sum scan + apply offset.
// ---------------------------------------------------------------------------
__global__ __launch_bounds__(256) void scanBC(const int* __restrict__ partial,
                                              const int* __restrict__ bsum,
                                              int* __restrict__ starts,
                                              int* __restrict__ cursor,
                                              int n, int ne, int nb) {
    __shared__ int sh[256];
    int t = threadIdx.x;
    int v = (t < nb) ? bsum[t] : 0;
    int val = v;
    sh[t] = val;
    __syncthreads();
#pragma unroll
    for (int off = 1; off < 256; off <<= 1) {
        int add = (t >= off) ? sh[t - off] : 0;
        __syncthreads();
        val += add;
        sh[t] = val;
        __syncthreads();
    }
    int myoff = (blockIdx.x == 0) ? 0 : sh[blockIdx.x - 1];
    int gid = blockIdx.x * 256 + t;
    if (gid < n) {
        int s = partial[gid] + myoff;
        starts[gid] = s;
        cursor[gid] = s;
    }
    if (gid == 0) starts[n] = ne;
}

// ---------------------------------------------------------------------------
// K_scatter: dst-segment permute + fp16 head weights: {src, w01, w23, pad}.
// ---------------------------------------------------------------------------
__global__ __launch_bounds__(256) void scatter_edges_w(const int* __restrict__ src,
                                                       const int* __restrict__ dst,
                                                       const float* __restrict__ a_src,
                                                       const float* __restrict__ a_dst,
                                                       int* __restrict__ cursor,
                                                       uint4* __restrict__ eperm, int ne) {
    int e = blockIdx.x * 256 + threadIdx.x;
    if (e < ne) {
        int s = src[e], t = dst[e];
        float4 as = *(const float4*)(a_src + (size_t)s * NH);
        float4 ad = *(const float4*)(a_dst + (size_t)t * NH);
        float A0 = as.x + ad.x, A1 = as.y + ad.y, A2 = as.z + ad.z, A3 = as.w + ad.w;
        A0 = (A0 > 0.f) ? A0 : 0.2f * A0;
        A1 = (A1 > 0.f) ? A1 : 0.2f * A1;
        A2 = (A2 > 0.f) ? A2 : 0.2f * A2;
        A3 = (A3 > 0.f) ? A3 : 0.2f * A3;
        float e0 = __expf(A0), e1 = __expf(A1), e2 = __expf(A2), e3 = __expf(A3);
        int pos = atomicAdd(&cursor[t], 1);
        uint4 ev;
        ev.x = (unsigned)s;
        ev.y = pack_half2(e0, e1);
        ev.z = pack_half2(e2, e3);
        ev.w = 0u;
        eperm[pos] = ev;
    }
}

// ---------------------------------------------------------------------------
// K_agg v5 (best known, 66.3us): one wave per node; per-chunk estage LDS
// broadcast; f32x2 accumulators (v_pk_fma_f32). 16-edge chunks.
// ---------------------------------------------------------------------------
#define PK8()                                                              \
    { f32x2 xlo = {bflo(xv.x), bfhi(xv.x)};                                \
      f32x2 xhi = {bflo(xv.y), bfhi(xv.y)};                                \
      acc2[0] += xlo * w01.x; acc2[1] += xhi * w01.x;                      \
      acc2[2] += xlo * w01.y; acc2[3] += xhi * w01.y;                      \
      acc2[4] += xlo * w23.x; acc2[5] += xhi * w23.x;                      \
      acc2[6] += xlo * w23.y; acc2[7] += xhi * w23.y; }

__global__ __launch_bounds__(256) void node_agg(const uint4* __restrict__ eperm,
                                                const int* __restrict__ starts,
                                                const uint2* __restrict__ xb2,
                                                unsigned* __restrict__ u, int n) {
    __shared__ uint4 estage[4][16];
    const int w = threadIdx.x >> 6;
    int node = blockIdx.x * 4 + w;
    int lane = threadIdx.x & 63;
    if (node >= n) return;
    const int slot = lane & 31;   // dim quad: dims 4*slot..4*slot+3
    const int half = lane >> 5;   // even/odd edge of each pair

    int s0 = starts[node], s1 = starts[node + 1];

    float den0 = 0.f, den1 = 0.f, den2 = 0.f, den3 = 0.f;
    f32x2 acc2[8];
#pragma unroll
    for (int j = 0; j < 8; ++j) acc2[j] = (f32x2){0.f, 0.f};

    for (int base = s0; base < s1; base += 16) {
        int rem = s1 - base; if (rem > 16) rem = 16;
        uint4 ev = {0u, 0u, 0u, 0u};
        if (lane < rem) ev = eperm[base + lane];
        if (lane < 16) estage[w][lane] = ev;    // zero-padded records for lane>=rem
        {   // denominator contributions (zero on lanes >= rem)
            float2 dl = h22f(ev.y), dh = h22f(ev.z);
            den0 += dl.x; den1 += dl.y; den2 += dh.x; den3 += dh.y;
        }
        if (rem == 16) {
#pragma unroll
            for (int pp = 0; pp < 8; ++pp) {
                uint4 e2 = estage[w][2 * pp + half];   // uniform per half -> LDS broadcast
                uint2 xv = xb2[(size_t)e2.x * 32 + slot];
                float2 w01 = h22f(e2.y), w23 = h22f(e2.z);
                PK8();
            }
        } else {
            for (int jj = 0; jj < rem; jj += 2) {
                int j2 = jj + half;
                bool valid = (j2 < rem);
                uint4 e2 = estage[w][valid ? j2 : jj];
                uint2 xv = xb2[(size_t)e2.x * 32 + slot];
                float2 w01 = h22f(e2.y), w23 = h22f(e2.z);
                float m = valid ? 1.f : 0.f;
                w01.x *= m; w01.y *= m; w23.x *= m; w23.y *= m;
                PK8();
            }
        }
    }

    // reduce denominators over all 64 lanes
#pragma unroll
    for (int off = 1; off < 64; off <<= 1) {
        den0 += __shfl_xor(den0, off);
        den1 += __shfl_xor(den1, off);
        den2 += __shfl_xor(den2, off);
        den3 += __shfl_xor(den3, off);
    }
    float i0 = (den0 > 0.f) ? 0.25f / den0 : 0.f;
    float i1 = (den1 > 0.f) ? 0.25f / den1 : 0.f;
    float i2 = (den2 > 0.f) ? 0.25f / den2 : 0.f;
    float i3 = (den3 > 0.f) ? 0.25f / den3 : 0.f;

    float v[16];
#pragma unroll
    for (int hh4 = 0; hh4 < 4; ++hh4) {
        float ih = (hh4 == 0) ? i0 : (hh4 == 1) ? i1 : (hh4 == 2) ? i2 : i3;
        v[hh4 * 4 + 0] = acc2[hh4 * 2].x * ih;
        v[hh4 * 4 + 1] = acc2[hh4 * 2].y * ih;
        v[hh4 * 4 + 2] = acc2[hh4 * 2 + 1].x * ih;
        v[hh4 * 4 + 3] = acc2[hh4 * 2 + 1].y * ih;
    }
    // combine even/odd halves
#pragma unroll
    for (int j = 0; j < 16; ++j) v[j] += __shfl_xor(v[j], 32);

    // store u: lane half stores heads {2*half, 2*half+1}
#pragma unroll
    for (int hh = 0; hh < 2; ++hh) {
        int h = half * 2 + hh;
        uint2 val;
        val.x = pack_bf16(v[h * 4 + 0], v[h * 4 + 1]);
        val.y = pack_bf16(v[h * 4 + 2], v[h * 4 + 3]);
        ((uint2*)u)[(size_t)node * 128 + h * 32 + slot] = val;
    }
}

// ---------------------------------------------------------------------------
// K_out v6: agg = u [N,512] @ Ws^T via MFMA. 64 rows/block (782 blocks,
// better occupancy/tail than 128-row), 4 waves x 16 rows. B chunk (32KB)
// staged in LDS per kc, shared by all waves; A streams direct from global.
// Register epilogue: bias + LN (shfl over 16-lane col group) + GELU + res.
// ---------------------------------------------------------------------------
__global__ __launch_bounds__(256) void gemm_out(
        const unsigned short* __restrict__ u, const unsigned short* __restrict__ Ws,
        const float* __restrict__ x, const float* __restrict__ bias,
        const float* __restrict__ gamma, const float* __restrict__ beta,
        float* __restrict__ out, int n) {
    __shared__ char Bs[32768];
    const int t = threadIdx.x;
    const int w = t >> 6, l = t & 63;
    const int e16 = l & 15, g16 = l >> 4;
    const int row0 = blockIdx.x * 64;

    int ar = row0 + w * 16 + e16; if (ar >= n) ar = n - 1;
    const unsigned short* ap = u + (size_t)ar * HD + g16 * 8;

    f32x4 acc[8];
#pragma unroll
    for (int nr = 0; nr < 8; ++nr) acc[nr] = (f32x4){0.f, 0.f, 0.f, 0.f};

    const int swz = (e16 & 7) << 4;
    for (int kc = 0; kc < 4; ++kc) {
        if (kc) __syncthreads();
#pragma unroll
        for (int i = 0; i < 8; ++i) {
            int c = t + i * 256;
            int nl = c >> 4, kb = c & 15;
            uint4 pv = *(const uint4*)(Ws + (size_t)nl * HD + kc * 128 + kb * 8);
            *(uint4*)(Bs + nl * 256 + ((kb * 16) ^ ((nl & 7) << 4))) = pv;
        }
        __syncthreads();

#pragma unroll
        for (int ks = 0; ks < 4; ++ks) {
            int koff = (ks * 64 + g16 * 16) ^ swz;
            bf16x8 a0 = *(const bf16x8*)(ap + kc * 128 + ks * 32);
#pragma unroll
            for (int nr = 0; nr < 8; ++nr) {
                bf16x8 b = *(const bf16x8*)(Bs + (nr * 16 + e16) * 256 + koff);
                acc[nr] = __builtin_amdgcn_mfma_f32_16x16x32_bf16(a0, b, acc[nr], 0, 0, 0);
            }
        }
    }

    float bias_l[8], gam_l[8], bet_l[8];
#pragma unroll
    for (int c = 0; c < 8; ++c) {
        bias_l[c] = bias[c * 16 + e16];
        gam_l[c]  = gamma[c * 16 + e16];
        bet_l[c]  = beta[c * 16 + e16];
    }
#pragma unroll
    for (int ri = 0; ri < 4; ++ri) {
        int grow = row0 + w * 16 + g16 * 4 + ri;
        float val[8];
        float s = 0.f, s2 = 0.f;
#pragma unroll
        for (int c = 0; c < 8; ++c) {
            val[c] = acc[c][ri] + bias_l[c];
            s += val[c]; s2 += val[c] * val[c];
        }
#pragma unroll
        for (int off = 1; off < 16; off <<= 1) {
            s += __shfl_xor(s, off);
            s2 += __shfl_xor(s2, off);
        }
        float mu = s * (1.0f / ND);
        float var = fmaxf(s2 * (1.0f / ND) - mu * mu, 0.0f);
        float inv = rsqrtf(var + 1e-5f);
        if (grow < n) {
#pragma unroll
            for (int c = 0; c < 8; ++c) {
                float y = (val[c] - mu) * inv * gam_l[c] + bet_l[c];
                y = 0.5f * y * (1.0f + erff(y * 0.70710678118654752f));
                out[(size_t)grow * ND + c * 16 + e16] =
                    y + x[(size_t)grow * ND + c * 16 + e16];
            }
        }
    }
}

// ---------------------------------------------------------------------------
extern "C" void kernel_launch(void* const* d_in, const int* in_sizes, int n_in,
                              void* d_out, int out_size, void* d_ws, size_t ws_size,
                              hipStream_t stream) {
    const float* x       = (const float*)d_in[0];
    const int*   edge    = (const int*)d_in[1];   // [2, E]: src row then dst row
    const float* W       = (const float*)d_in[2];
    const float* att_src = (const float*)d_in[3];
    const float* att_dst = (const float*)d_in[4];
    const float* bias    = (const float*)d_in[5];
    const float* gamma   = (const float*)d_in[6];
    const float* beta    = (const float*)d_in[7];
    float* out = (float*)d_out;

    const int n  = in_sizes[0] / ND;   // 50000
    const int ne = in_sizes[1] / 2;    // 800000
    const int* src = edge;
    const int* dst = edge + ne;

    const int nb  = (n + 255) / 256;   // 196 (<256)
    const int nbA = (n + 3) / 4;       // k_a_xb blocks (12500)

    char* wsp = (char*)d_ws;
    unsigned* xb        = (unsigned*)wsp;        wsp += (size_t)n * 64 * sizeof(unsigned);   // bf16 x copy
    unsigned short* u   = (unsigned short*)wsp;  wsp += (size_t)n * HD * sizeof(short);      // weighted sums
    unsigned short* Ws  = (unsigned short*)wsp;  wsp += (size_t)ND * HD * sizeof(short);     // [j][K] bf16
    float* pt      = (float*)wsp;               wsp += (size_t)8 * ND * sizeof(float);
    float* a_src   = (float*)wsp;               wsp += (size_t)n * NH * sizeof(float);
    float* a_dst   = (float*)wsp;               wsp += (size_t)n * NH * sizeof(float);
    uint4* eperm   = (uint4*)wsp;               wsp += (size_t)ne * sizeof(uint4);
    int*   cnt     = (int*)wsp;                 wsp += (size_t)n * sizeof(int);
    int*   partial = (int*)wsp;                 wsp += (size_t)n * sizeof(int);
    int*   bsum    = (int*)wsp;                 wsp += 256 * sizeof(int);
    int*   starts  = (int*)wsp;                 wsp += (size_t)(n + 1) * sizeof(int);
    int*   cursor  = (int*)wsp;                 wsp += (size_t)n * sizeof(int);

    (void)hipMemsetAsync(cnt, 0, (size_t)n * sizeof(int), stream);

    prep_misc<<<48 + (ne + 255) / 256, 256, 0, stream>>>(W, att_src, att_dst,
                                                         Ws, pt, dst, cnt, ne);

    ka_scanA<<<nbA + nb, 256, 0, stream>>>(x, pt, xb, a_src, a_dst,
                                           cnt, partial, bsum, n, nbA);

    scanBC<<<nb, 256, 0, stream>>>(partial, bsum, starts, cursor, n, ne, nb);

    scatter_edges_w<<<(ne + 255) / 256, 256, 0, stream>>>(src, dst, a_src, a_dst,
                                                          cursor, eperm, ne);

    node_agg<<<(n + 3) / 4, 256, 0, stream>>>(eperm, starts, (const uint2*)xb,
                                              (unsigned*)u, n);

    gemm_out<<<(n + 63) / 64, 256, 0, stream>>>(u, Ws, x, bias, gamma, beta, out, n);
}

// Round 18
// 207.947 us; speedup vs baseline: 1.3580x; 1.0126x over previous
//
#include <hip/hip_runtime.h>
#include <hip/hip_bf16.h>
#include <hip/hip_fp16.h>
#include <math.h>

#define ND 128      // feature dim D
#define NH 4        // heads
#define HD 512      // H*D

typedef __attribute__((ext_vector_type(8))) short bf16x8;
typedef __attribute__((ext_vector_type(4))) float f32x4;
typedef __attribute__((ext_vector_type(2))) float f32x2;

__device__ __forceinline__ unsigned pack_bf16(float a, float b) {
    unsigned ua = __float_as_uint(a), ub = __float_as_uint(b);
    ua = (ua + 0x7fffu + ((ua >> 16) & 1u)) >> 16;
    ub = (ub + 0x7fffu + ((ub >> 16) & 1u)) >> 16;
    return ua | (ub << 16);
}
__device__ __forceinline__ unsigned short bf16r(float a) {
    unsigned ua = __float_as_uint(a);
    return (unsigned short)((ua + 0x7fffu + ((ua >> 16) & 1u)) >> 16);
}
__device__ __forceinline__ float bflo(unsigned u) { return __uint_as_float(u << 16); }
__device__ __forceinline__ float bfhi(unsigned u) { return __uint_as_float(u & 0xffff0000u); }
__device__ __forceinline__ unsigned pack_half2(float a, float b) {
    __half ha = __float2half(a), hb = __float2half(b);
    return (unsigned)__half_as_ushort(ha) | ((unsigned)__half_as_ushort(hb) << 16);
}
__device__ __forceinline__ float2 h22f(unsigned u) {
    __half2 h = *(__half2*)&u;
    return __half22float2(h);
}

// ---------------------------------------------------------------------------
// K0 v2: blocks [0,16): W 64x64 LDS-tile transposes -> Ws[j][h*128+k] bf16.
//        blocks [16,48): pt — wave per k (coalesced W row reads + shfl).
//        blocks [48, ...): dst histogram.
// ---------------------------------------------------------------------------
__global__ __launch_bounds__(256) void prep_misc(const float* __restrict__ W,
                                                 const float* __restrict__ att_src,
                                                 const float* __restrict__ att_dst,
                                                 unsigned short* __restrict__ Ws,
                                                 float* __restrict__ pt,
                                                 const int* __restrict__ dst,
                                                 int* __restrict__ cnt, int ne) {
    int b = blockIdx.x;
    if (b < 16) {
        __shared__ float tile[64][65];
        int h = b >> 2, rt = (b >> 1) & 1, ct = b & 1;
        int tx = threadIdx.x;
        int rr = tx >> 6, c = tx & 63;
#pragma unroll
        for (int i = 0; i < 16; ++i) {
            int r = i * 4 + rr;
            tile[r][c] = W[(size_t)(rt * 64 + r) * HD + h * ND + ct * 64 + c];
        }
        __syncthreads();
#pragma unroll
        for (int i = 0; i < 16; ++i) {
            int r = i * 4 + rr;   // j-local
            Ws[(size_t)(ct * 64 + r) * HD + h * ND + rt * 64 + c] = bf16r(tile[c][r]);
        }
    } else if (b < 48) {
        int w = threadIdx.x >> 6, lane = threadIdx.x & 63;
        int k = (b - 16) * 4 + w;   // 0..127
#pragma unroll
        for (int h = 0; h < NH; ++h) {
            float2 wv = ((const float2*)(W + (size_t)k * HD + h * ND))[lane];
            float2 as = ((const float2*)(att_src + h * ND))[lane];
            float2 ad = ((const float2*)(att_dst + h * ND))[lane];
            float ps = wv.x * as.x + wv.y * as.y;
            float pd = wv.x * ad.x + wv.y * ad.y;
#pragma unroll
            for (int off = 1; off < 64; off <<= 1) {
                ps += __shfl_xor(ps, off);
                pd += __shfl_xor(pd, off);
            }
            if (lane == 0) {
                pt[h * ND + k] = ps;
                pt[(4 + h) * ND + k] = pd;
            }
        }
    } else {
        int e = (b - 48) * 256 + threadIdx.x;
        if (e < ne) atomicAdd(&cnt[dst[e]], 1);
    }
}

// ---------------------------------------------------------------------------
// K1 fused: blocks [0, nbA): k_a_xb (emits FP8 e4m3 x copy + attention
// logits); blocks [nbA, nbA+nbS): scanA over cnt.
// ---------------------------------------------------------------------------
__global__ __launch_bounds__(256) void ka_scanA(const float* __restrict__ x,
                                                const float* __restrict__ pt,
                                                unsigned* __restrict__ xb8,
                                                float* __restrict__ a_src,
                                                float* __restrict__ a_dst,
                                                const int* __restrict__ cnt,
                                                int* __restrict__ partial,
                                                int* __restrict__ bsum,
                                                int n, int nbA) {
    __shared__ float pl[8 * ND];
    __shared__ int sh[256];
    if ((int)blockIdx.x < nbA) {
        { int t = threadIdx.x; ((float4*)pl)[t] = ((const float4*)pt)[t]; }
        __syncthreads();
        int wave = (blockIdx.x * 256 + threadIdx.x) >> 6;
        int lane = threadIdx.x & 63;
        if (wave >= n) return;
        float2 xv = ((const float2*)(x + (size_t)wave * ND))[lane];
        // fp8 pack: lane's 2 dims -> 16 bits; lane L<32 combines lanes 2L,2L+1
        int pk16 = __builtin_amdgcn_cvt_pk_fp8_f32(xv.x, xv.y, 0, false);
        int pkA = __shfl(pk16, (lane & 31) * 2);
        int pkB = __shfl(pk16, (lane & 31) * 2 + 1);
        if (lane < 32)
            xb8[(size_t)wave * 32 + lane] =
                ((unsigned)pkA & 0xffffu) | ((unsigned)pkB << 16);
#pragma unroll
        for (int o = 0; o < 8; ++o) {
            float2 pv = ((const float2*)(pl + o * ND))[lane];
            float v = xv.x * pv.x + xv.y * pv.y;
#pragma unroll
            for (int off = 1; off < 64; off <<= 1) v += __shfl_xor(v, off);
            if (lane == 0) {
                if (o < 4) a_src[(size_t)wave * NH + o] = v;
                else       a_dst[(size_t)wave * NH + (o - 4)] = v;
            }
        }
    } else {
        int bid = blockIdx.x - nbA;
        int gid = bid * 256 + threadIdx.x;
        int v = (gid < n) ? cnt[gid] : 0;
        int val = v;
        sh[threadIdx.x] = val;
        __syncthreads();
#pragma unroll
        for (int off = 1; off < 256; off <<= 1) {
            int add = (threadIdx.x >= off) ? sh[threadIdx.x - off] : 0;
            __syncthreads();
            val += add;
            sh[threadIdx.x] = val;
            __syncthreads();
        }
        if (gid < n) partial[gid] = val - v;
        if (threadIdx.x == 255) bsum[bid] = val;
    }
}

// ---------------------------------------------------------------------------
// scanBC: redundant block-sum scan + apply offset.
// ---------------------------------------------------------------------------
__global__ __launch_bounds__(256) void scanBC(const int* __restrict__ partial,
                                              const int* __restrict__ bsum,
                                              int* __restrict__ starts,
                                              int* __restrict__ cursor,
                                              int n, int ne, int nb) {
    __shared__ int sh[256];
    int t = threadIdx.x;
    int v = (t < nb) ? bsum[t] : 0;
    int val = v;
    sh[t] = val;
    __syncthreads();
#pragma unroll
    for (int off = 1; off < 256; off <<= 1) {
        int add = (t >= off) ? sh[t - off] : 0;
        __syncthreads();
        val += add;
        sh[t] = val;
        __syncthreads();
    }
    int myoff = (blockIdx.x == 0) ? 0 : sh[blockIdx.x - 1];
    int gid = blockIdx.x * 256 + t;
    if (gid < n) {
        int s = partial[gid] + myoff;
        starts[gid] = s;
        cursor[gid] = s;
    }
    if (gid == 0) starts[n] = ne;
}

// ---------------------------------------------------------------------------
// K_scatter: dst-segment permute + fp16 head weights: {src, w01, w23, pad}.
// ---------------------------------------------------------------------------
__global__ __launch_bounds__(256) void scatter_edges_w(const int* __restrict__ src,
                                                       const int* __restrict__ dst,
                                                       const float* __restrict__ a_src,
                                                       const float* __restrict__ a_dst,
                                                       int* __restrict__ cursor,
                                                       uint4* __restrict__ eperm, int ne) {
    int e = blockIdx.x * 256 + threadIdx.x;
    if (e < ne) {
        int s = src[e], t = dst[e];
        float4 as = *(const float4*)(a_src + (size_t)s * NH);
        float4 ad = *(const float4*)(a_dst + (size_t)t * NH);
        float A0 = as.x + ad.x, A1 = as.y + ad.y, A2 = as.z + ad.z, A3 = as.w + ad.w;
        A0 = (A0 > 0.f) ? A0 : 0.2f * A0;
        A1 = (A1 > 0.f) ? A1 : 0.2f * A1;
        A2 = (A2 > 0.f) ? A2 : 0.2f * A2;
        A3 = (A3 > 0.f) ? A3 : 0.2f * A3;
        float e0 = __expf(A0), e1 = __expf(A1), e2 = __expf(A2), e3 = __expf(A3);
        int pos = atomicAdd(&cursor[t], 1);
        uint4 ev;
        ev.x = (unsigned)s;
        ev.y = pack_half2(e0, e1);
        ev.z = pack_half2(e2, e3);
        ev.w = 0u;
        eperm[pos] = ev;
    }
}

// ---------------------------------------------------------------------------
// K_agg v7 (fp8 gather): one wave per node; per-chunk estage LDS broadcast;
// gather = ONE uint per lane (4 fp8 dims, 2 cache lines per edge vs 4 for
// bf16); decode via hardware cvt_pk_f32_fp8; f32x2 accumulators.
// ---------------------------------------------------------------------------
__global__ __launch_bounds__(256) void node_agg(const uint4* __restrict__ eperm,
                                                const int* __restrict__ starts,
                                                const unsigned* __restrict__ xb8,
                                                unsigned* __restrict__ u, int n) {
    __shared__ uint4 estage[4][16];
    const int w = threadIdx.x >> 6;
    int node = blockIdx.x * 4 + w;
    int lane = threadIdx.x & 63;
    if (node >= n) return;
    const int slot = lane & 31;   // dim quad: dims 4*slot..4*slot+3
    const int half = lane >> 5;   // even/odd edge of each pair

    int s0 = starts[node], s1 = starts[node + 1];

    float den0 = 0.f, den1 = 0.f, den2 = 0.f, den3 = 0.f;
    f32x2 acc2[8];
#pragma unroll
    for (int j = 0; j < 8; ++j) acc2[j] = (f32x2){0.f, 0.f};

    for (int base = s0; base < s1; base += 16) {
        int rem = s1 - base; if (rem > 16) rem = 16;
        uint4 ev = {0u, 0u, 0u, 0u};
        if (lane < rem) ev = eperm[base + lane];
        if (lane < 16) estage[w][lane] = ev;    // zero-padded records for lane>=rem
        {   // denominator contributions (zero on lanes >= rem)
            float2 dl = h22f(ev.y), dh = h22f(ev.z);
            den0 += dl.x; den1 += dl.y; den2 += dh.x; den3 += dh.y;
        }
        if (rem == 16) {
#pragma unroll
            for (int pp = 0; pp < 8; ++pp) {
                uint4 e2 = estage[w][2 * pp + half];   // uniform per half -> LDS broadcast
                unsigned xv8 = xb8[(size_t)e2.x * 32 + slot];
                f32x2 xlo = __builtin_amdgcn_cvt_pk_f32_fp8((int)xv8, false);
                f32x2 xhi = __builtin_amdgcn_cvt_pk_f32_fp8((int)xv8, true);
                float2 w01 = h22f(e2.y), w23 = h22f(e2.z);
                acc2[0] += xlo * w01.x; acc2[1] += xhi * w01.x;
                acc2[2] += xlo * w01.y; acc2[3] += xhi * w01.y;
                acc2[4] += xlo * w23.x; acc2[5] += xhi * w23.x;
                acc2[6] += xlo * w23.y; acc2[7] += xhi * w23.y;
            }
        } else {
            for (int jj = 0; jj < rem; jj += 2) {
                int j2 = jj + half;
                bool valid = (j2 < rem);
                uint4 e2 = estage[w][valid ? j2 : jj];
                unsigned xv8 = xb8[(size_t)e2.x * 32 + slot];
                f32x2 xlo = __builtin_amdgcn_cvt_pk_f32_fp8((int)xv8, false);
                f32x2 xhi = __builtin_amdgcn_cvt_pk_f32_fp8((int)xv8, true);
                float2 w01 = h22f(e2.y), w23 = h22f(e2.z);
                float m = valid ? 1.f : 0.f;
                w01.x *= m; w01.y *= m; w23.x *= m; w23.y *= m;
                acc2[0] += xlo * w01.x; acc2[1] += xhi * w01.x;
                acc2[2] += xlo * w01.y; acc2[3] += xhi * w01.y;
                acc2[4] += xlo * w23.x; acc2[5] += xhi * w23.x;
                acc2[6] += xlo * w23.y; acc2[7] += xhi * w23.y;
            }
        }
    }

    // reduce denominators over all 64 lanes
#pragma unroll
    for (int off = 1; off < 64; off <<= 1) {
        den0 += __shfl_xor(den0, off);
        den1 += __shfl_xor(den1, off);
        den2 += __shfl_xor(den2, off);
        den3 += __shfl_xor(den3, off);
    }
    float i0 = (den0 > 0.f) ? 0.25f / den0 : 0.f;
    float i1 = (den1 > 0.f) ? 0.25f / den1 : 0.f;
    float i2 = (den2 > 0.f) ? 0.25f / den2 : 0.f;
    float i3 = (den3 > 0.f) ? 0.25f / den3 : 0.f;

    float v[16];
#pragma unroll
    for (int hh4 = 0; hh4 < 4; ++hh4) {
        float ih = (hh4 == 0) ? i0 : (hh4 == 1) ? i1 : (hh4 == 2) ? i2 : i3;
        v[hh4 * 4 + 0] = acc2[hh4 * 2].x * ih;
        v[hh4 * 4 + 1] = acc2[hh4 * 2].y * ih;
        v[hh4 * 4 + 2] = acc2[hh4 * 2 + 1].x * ih;
        v[hh4 * 4 + 3] = acc2[hh4 * 2 + 1].y * ih;
    }
    // combine even/odd halves
#pragma unroll
    for (int j = 0; j < 16; ++j) v[j] += __shfl_xor(v[j], 32);

    // store u: lane half stores heads {2*half, 2*half+1}
#pragma unroll
    for (int hh = 0; hh < 2; ++hh) {
        int h = half * 2 + hh;
        uint2 val;
        val.x = pack_bf16(v[h * 4 + 0], v[h * 4 + 1]);
        val.y = pack_bf16(v[h * 4 + 2], v[h * 4 + 3]);
        ((uint2*)u)[(size_t)node * 128 + h * 32 + slot] = val;
    }
}

// ---------------------------------------------------------------------------
// K_out v6 (R17-proven): agg = u [N,512] @ Ws^T via MFMA. 64 rows/block,
// B chunk (32KB) in LDS per kc; A streams direct from global; register
// epilogue: bias + LN (shfl over 16-lane col group) + GELU + residual.
// ---------------------------------------------------------------------------
__global__ __launch_bounds__(256) void gemm_out(
        const unsigned short* __restrict__ u, const unsigned short* __restrict__ Ws,
        const float* __restrict__ x, const float* __restrict__ bias,
        const float* __restrict__ gamma, const float* __restrict__ beta,
        float* __restrict__ out, int n) {
    __shared__ char Bs[32768];
    const int t = threadIdx.x;
    const int w = t >> 6, l = t & 63;
    const int e16 = l & 15, g16 = l >> 4;
    const int row0 = blockIdx.x * 64;

    int ar = row0 + w * 16 + e16; if (ar >= n) ar = n - 1;
    const unsigned short* ap = u + (size_t)ar * HD + g16 * 8;

    f32x4 acc[8];
#pragma unroll
    for (int nr = 0; nr < 8; ++nr) acc[nr] = (f32x4){0.f, 0.f, 0.f, 0.f};

    const int swz = (e16 & 7) << 4;
    for (int kc = 0; kc < 4; ++kc) {
        if (kc) __syncthreads();
#pragma unroll
        for (int i = 0; i < 8; ++i) {
            int c = t + i * 256;
            int nl = c >> 4, kb = c & 15;
            uint4 pv = *(const uint4*)(Ws + (size_t)nl * HD + kc * 128 + kb * 8);
            *(uint4*)(Bs + nl * 256 + ((kb * 16) ^ ((nl & 7) << 4))) = pv;
        }
        __syncthreads();

#pragma unroll
        for (int ks = 0; ks < 4; ++ks) {
            int koff = (ks * 64 + g16 * 16) ^ swz;
            bf16x8 a0 = *(const bf16x8*)(ap + kc * 128 + ks * 32);
#pragma unroll
            for (int nr = 0; nr < 8; ++nr) {
                bf16x8 b = *(const bf16x8*)(Bs + (nr * 16 + e16) * 256 + koff);
                acc[nr] = __builtin_amdgcn_mfma_f32_16x16x32_bf16(a0, b, acc[nr], 0, 0, 0);
            }
        }
    }

    float bias_l[8], gam_l[8], bet_l[8];
#pragma unroll
    for (int c = 0; c < 8; ++c) {
        bias_l[c] = bias[c * 16 + e16];
        gam_l[c]  = gamma[c * 16 + e16];
        bet_l[c]  = beta[c * 16 + e16];
    }
#pragma unroll
    for (int ri = 0; ri < 4; ++ri) {
        int grow = row0 + w * 16 + g16 * 4 + ri;
        float val[8];
        float s = 0.f, s2 = 0.f;
#pragma unroll
        for (int c = 0; c < 8; ++c) {
            val[c] = acc[c][ri] + bias_l[c];
            s += val[c]; s2 += val[c] * val[c];
        }
#pragma unroll
        for (int off = 1; off < 16; off <<= 1) {
            s += __shfl_xor(s, off);
            s2 += __shfl_xor(s2, off);
        }
        float mu = s * (1.0f / ND);
        float var = fmaxf(s2 * (1.0f / ND) - mu * mu, 0.0f);
        float inv = rsqrtf(var + 1e-5f);
        if (grow < n) {
#pragma unroll
            for (int c = 0; c < 8; ++c) {
                float y = (val[c] - mu) * inv * gam_l[c] + bet_l[c];
                y = 0.5f * y * (1.0f + erff(y * 0.70710678118654752f));
                out[(size_t)grow * ND + c * 16 + e16] =
                    y + x[(size_t)grow * ND + c * 16 + e16];
            }
        }
    }
}

// ---------------------------------------------------------------------------
extern "C" void kernel_launch(void* const* d_in, const int* in_sizes, int n_in,
                              void* d_out, int out_size, void* d_ws, size_t ws_size,
                              hipStream_t stream) {
    const float* x       = (const float*)d_in[0];
    const int*   edge    = (const int*)d_in[1];   // [2, E]: src row then dst row
    const float* W       = (const float*)d_in[2];
    const float* att_src = (const float*)d_in[3];
    const float* att_dst = (const float*)d_in[4];
    const float* bias    = (const float*)d_in[5];
    const float* gamma   = (const float*)d_in[6];
    const float* beta    = (const float*)d_in[7];
    float* out = (float*)d_out;

    const int n  = in_sizes[0] / ND;   // 50000
    const int ne = in_sizes[1] / 2;    // 800000
    const int* src = edge;
    const int* dst = edge + ne;

    const int nb  = (n + 255) / 256;   // 196 (<256)
    const int nbA = (n + 3) / 4;       // k_a_xb blocks (12500)

    char* wsp = (char*)d_ws;
    unsigned* xb8       = (unsigned*)wsp;        wsp += (size_t)n * 32 * sizeof(unsigned);   // fp8 x copy
    unsigned short* u   = (unsigned short*)wsp;  wsp += (size_t)n * HD * sizeof(short);      // weighted sums
    unsigned short* Ws  = (unsigned short*)wsp;  wsp += (size_t)ND * HD * sizeof(short);     // [j][K] bf16
    float* pt      = (float*)wsp;               wsp += (size_t)8 * ND * sizeof(float);
    float* a_src   = (float*)wsp;               wsp += (size_t)n * NH * sizeof(float);
    float* a_dst   = (float*)wsp;               wsp += (size_t)n * NH * sizeof(float);
    uint4* eperm   = (uint4*)wsp;               wsp += (size_t)ne * sizeof(uint4);
    int*   cnt     = (int*)wsp;                 wsp += (size_t)n * sizeof(int);
    int*   partial = (int*)wsp;                 wsp += (size_t)n * sizeof(int);
    int*   bsum    = (int*)wsp;                 wsp += 256 * sizeof(int);
    int*   starts  = (int*)wsp;                 wsp += (size_t)(n + 1) * sizeof(int);
    int*   cursor  = (int*)wsp;                 wsp += (size_t)n * sizeof(int);

    (void)hipMemsetAsync(cnt, 0, (size_t)n * sizeof(int), stream);

    prep_misc<<<48 + (ne + 255) / 256, 256, 0, stream>>>(W, att_src, att_dst,
                                                         Ws, pt, dst, cnt, ne);

    ka_scanA<<<nbA + nb, 256, 0, stream>>>(x, pt, xb8, a_src, a_dst,
                                           cnt, partial, bsum, n, nbA);

    scanBC<<<nb, 256, 0, stream>>>(partial, bsum, starts, cursor, n, ne, nb);

    scatter_edges_w<<<(ne + 255) / 256, 256, 0, stream>>>(src, dst, a_src, a_dst,
                                                          cursor, eperm, ne);

    node_agg<<<(n + 3) / 4, 256, 0, stream>>>(eperm, starts, xb8, (unsigned*)u, n);

    gemm_out<<<(n + 63) / 64, 256, 0, stream>>>(u, Ws, x, bias, gamma, beta, out, n);
}